// Round 1
// baseline (154.751 us; speedup 1.0000x reference)
//
#include <hip/hip_runtime.h>
#include <hip/hip_bf16.h>
#include <math.h>

#define N_BATCH 256
#define C_CH    2048
#define HW      49
#define SIZE7   7
#define S_SPLIT 8
#define C_PER   (C_CH / S_SPLIT)   // 256 channels per block
#define BLOCK   256
#define WAVES   4                  // 256/64

// Kernel 1: per-(n, channel-split) partial sums.
// For each spatial position p (lane), accumulate over channels:
//   q0: sum x          (for argmax of channel-mean)
//   q1: sum x*W1[0,c]  (anchor dot, row 0)
//   q2: sum x*W1[1,c]  (anchor dot, row 1)
//   q3: sum x*W2[0,c]  (pred term, out 0)
//   q4: sum x*W2[1,c]  (pred term, out 1)
__global__ __launch_bounds__(BLOCK) void rpp_partial_kernel(
    const float* __restrict__ x, const float* __restrict__ Wlin,
    float* __restrict__ ws) {
  const int bid  = blockIdx.x;          // n * S_SPLIT + s
  const int n    = bid >> 3;            // / S_SPLIT
  const int s    = bid & (S_SPLIT - 1);
  const int tid  = threadIdx.x;
  const int lane = tid & 63;
  const int wave = tid >> 6;

  __shared__ __align__(16) float w_s[4][C_PER];  // W1r0, W1r1, W2r0, W2r1
  __shared__ float red[WAVES][5][64];

  const int cbase = s * C_PER;
  // Stage this split's weight slices into LDS. Wlin is (2, 2C):
  //   W1[o,c] = Wlin[o*2C + c],  W2[o,c] = Wlin[o*2C + C + c]
  for (int i = tid; i < 4 * C_PER; i += BLOCK) {
    const int q = i >> 8;          // / C_PER
    const int c = i & (C_PER - 1);
    const int off = (q & 1) * (2 * C_CH) + (q >> 1) * C_CH;
    w_s[q][c] = Wlin[off + cbase + c];
  }
  __syncthreads();

  // Lane p reads x[n, c, p]; lanes >= 49 clamp to p=0 (same cache line, unused).
  const int lp = (lane < HW) ? lane : 0;
  const int wbase = wave * 64;   // each wave: 64 contiguous channels
  const float* xp = x + (size_t)n * C_CH * HW + (size_t)(cbase + wbase) * HW + lp;

  float a0 = 0.f, a1 = 0.f, a2 = 0.f, a3 = 0.f, a4 = 0.f;
#pragma unroll 4
  for (int c = 0; c < 64; c += 4, xp += 4 * HW) {
    const float v0 = xp[0 * HW];
    const float v1 = xp[1 * HW];
    const float v2 = xp[2 * HW];
    const float v3 = xp[3 * HW];
    const float4 w0 = *(const float4*)&w_s[0][wbase + c];
    const float4 w1 = *(const float4*)&w_s[1][wbase + c];
    const float4 w2 = *(const float4*)&w_s[2][wbase + c];
    const float4 w3 = *(const float4*)&w_s[3][wbase + c];
    a0 += (v0 + v1) + (v2 + v3);
    a1 = fmaf(v0, w0.x, fmaf(v1, w0.y, fmaf(v2, w0.z, fmaf(v3, w0.w, a1))));
    a2 = fmaf(v0, w1.x, fmaf(v1, w1.y, fmaf(v2, w1.z, fmaf(v3, w1.w, a2))));
    a3 = fmaf(v0, w2.x, fmaf(v1, w2.y, fmaf(v2, w2.z, fmaf(v3, w2.w, a3))));
    a4 = fmaf(v0, w3.x, fmaf(v1, w3.y, fmaf(v2, w3.z, fmaf(v3, w3.w, a4))));
  }

  red[wave][0][lane] = a0;
  red[wave][1][lane] = a1;
  red[wave][2][lane] = a2;
  red[wave][3][lane] = a3;
  red[wave][4][lane] = a4;
  __syncthreads();

  // Reduce 4 waves -> 5*64 partials, store to workspace.
  for (int i = tid; i < 5 * 64; i += BLOCK) {
    const int q = i >> 6;
    const int l = i & 63;
    ws[(size_t)bid * 320 + i] =
        red[0][q][l] + red[1][q][l] + red[2][q][l] + red[3][q][l];
  }
}

// Kernel 2: one wave per batch n. Reduce splits, argmax, epilogue.
__global__ __launch_bounds__(64) void rpp_final_kernel(
    const float* __restrict__ ws, const float* __restrict__ b,
    float* __restrict__ out) {
  const int n = blockIdx.x;
  const int lane = threadIdx.x;   // p = lane for p < 49

  float s0 = 0.f, s1 = 0.f, s2 = 0.f, s3 = 0.f, s4 = 0.f;
  const float* base = ws + (size_t)n * S_SPLIT * 320;
#pragma unroll
  for (int s = 0; s < S_SPLIT; s++) {
    const float* bs = base + s * 320;
    s0 += bs[0 * 64 + lane];
    s1 += bs[1 * 64 + lane];
    s2 += bs[2 * 64 + lane];
    s3 += bs[3 * 64 + lane];
    s4 += bs[4 * 64 + lane];
  }

  // argmax over p<49 of channel-sum (same order as mean); first-max tie-break.
  float v = (lane < HW) ? s0 : -INFINITY;
  int vi = lane;
#pragma unroll
  for (int off = 32; off; off >>= 1) {
    const float ov = __shfl_down(v, off);
    const int oi = __shfl_down(vi, off);
    if (ov > v || (ov == v && oi < vi)) { v = ov; vi = oi; }
  }
  const int idx = __shfl(vi, 0);

  // anchor dot products: (max_feat @ W1^T)[n, o]
  const float anc0 = __shfl(s1, idx);
  const float anc1 = __shfl(s2, idx);
  const float b0 = b[0], b1 = b[1];

  float pred0 = fmaxf(s3 + anc0 + b0, 0.f);
  float pred1 = fmaxf(s4 + anc1 + b1, 0.f);
  if (lane == idx) { pred0 = 0.f; pred1 = 0.f; }

  const int li = lane / SIZE7, lj = lane % SIZE7;
  const int ai = idx / SIZE7, aj = idx % SIZE7;
  const float ri = (float)(li - ai) * (1.0f / SIZE7);
  const float rj = (float)(lj - aj) * (1.0f / SIZE7);
  const float rdist = sqrtf(ri * ri + rj * rj);
  // (atan2/pi + 1)/2 ; atan2f(0,0)=0 matches jnp at the anchor.
  const float rangle = atan2f(rj, ri) * 0.15915494309189535f + 0.5f;

  float dl = pred0 - rdist;
  dl *= dl;
  float gap = pred1 - rangle;
  if (gap < 0.f) gap += 1.f;

  // mean of gap over the 49 valid positions
  float g = (lane < HW) ? gap : 0.f;
#pragma unroll
  for (int off = 32; off; off >>= 1) g += __shfl_down(g, off);
  const float mean = __shfl(g, 0) * (1.0f / HW);
  gap -= mean;

  if (lane < HW) out[(size_t)n * HW + lane] = dl + gap * gap;
}

extern "C" void kernel_launch(void* const* d_in, const int* in_sizes, int n_in,
                              void* d_out, int out_size, void* d_ws, size_t ws_size,
                              hipStream_t stream) {
  const float* x    = (const float*)d_in[0];
  const float* Wlin = (const float*)d_in[1];
  const float* b    = (const float*)d_in[2];
  float* out = (float*)d_out;
  float* ws  = (float*)d_ws;   // 2048 * 320 * 4 B = 2.62 MB, fully rewritten each call

  hipLaunchKernelGGL(rpp_partial_kernel, dim3(N_BATCH * S_SPLIT), dim3(BLOCK), 0,
                     stream, x, Wlin, ws);
  hipLaunchKernelGGL(rpp_final_kernel, dim3(N_BATCH), dim3(64), 0,
                     stream, ws, b, out);
}